// Round 1
// 178.272 us; speedup vs baseline: 1.0354x; 1.0354x over previous
//
#include <hip/hip_runtime.h>

// RoDAlignMax: features [4,256,64,64] f32, rois [2048,5] -> out [2048,256,9,9] f32
// Grid samples are exactly (7i, 7j): bilinear degenerates to a gather.
// Kernel 1: gather G[b][p][c] (p = i*10+j, 100 points) = F[b,c,7i,7j]  (400 KB, L2-resident)
// Kernel 2: one wave per (roi, channel-quarter): masked 10x10 -> 2x2/s1 maxpool -> 9x9,
//           LDS transpose (stride exactly 81, mirrors output) -> b128 reads + dwordx4 stores.

#define NB 4
#define NC 256
#define HW 64
#define NR 2048

__global__ __launch_bounds__(256) void rod_gather(const float* __restrict__ F,
                                                  float* __restrict__ G) {
    int idx = blockIdx.x * 256 + threadIdx.x;      // < 4*100*256 = 102400
    int c = idx & 255;
    int t = idx >> 8;                              // b*100 + p
    int p = t % 100;
    int b = t / 100;
    int i = p / 10, j = p - i * 10;
    // F[((b*256 + c)*64 + 7i)*64 + 7j]
    G[idx] = F[((b * NC + c) << 12) + i * 448 + j * 7];
}

__global__ __launch_bounds__(64) void rod_main(const float* __restrict__ G,
                                               const float* __restrict__ rois,
                                               float* __restrict__ out) {
    // 64 channels x 81 outputs, layout identical to the global output slice.
    // stride 81 (odd) -> conflict-free scalar writes; 16B-aligned base -> b128 reads.
    __shared__ __align__(16) float lds[64 * 81];   // 20736 B -> 7 blocks/CU
    const int tid = threadIdx.x;
    const int r   = blockIdx.x >> 2;
    const int q   = blockIdx.x & 3;                // channel quarter
    const int c   = (q << 6) + tid;

    const float x1 = rois[r * 5 + 1] * 0.25f;
    const float y1 = rois[r * 5 + 2] * 0.25f;
    const float x2 = rois[r * 5 + 3] * 0.25f;
    const float y2 = rois[r * 5 + 4] * 0.25f;
    const int  b   = (int)rois[r * 5 + 0];

    bool inw[10], inh[10];                         // wave-uniform (SGPR) masks
    #pragma unroll
    for (int j = 0; j < 10; ++j) {
        float s = 7.0f * (float)j;                 // exact grid coordinate
        inw[j] = (s >= x1) && (s <= x2);
        inh[j] = (s >= y1) && (s <= y2);
    }

    // G[b][p][c]: stride 256 floats per p; lanes (consecutive c) coalesce each load.
    const float* gb = G + (size_t)b * 100 * NC + c;

    float raw1[10];                                // row i raw values (in flight)
    float vprev[10];
    {
        float raw0[10];
        #pragma unroll
        for (int j = 0; j < 10; ++j) raw0[j] = gb[j * NC];          // row 0
        #pragma unroll
        for (int j = 0; j < 10; ++j) raw1[j] = gb[(10 + j) * NC];   // prefetch row 1
        #pragma unroll
        for (int j = 0; j < 10; ++j) vprev[j] = (inh[0] && inw[j]) ? 0.0f : raw0[j];
    }

    #pragma unroll
    for (int i = 1; i < 10; ++i) {
        float rawn[10];
        if (i < 9) {                               // prefetch row i+1 before consuming row i
            #pragma unroll
            for (int j = 0; j < 10; ++j) rawn[j] = gb[((i + 1) * 10 + j) * NC];
        }
        float vcur[10];
        #pragma unroll
        for (int j = 0; j < 10; ++j) vcur[j] = (inh[i] && inw[j]) ? 0.0f : raw1[j];
        float rm[10];
        #pragma unroll
        for (int j = 0; j < 10; ++j) rm[j] = fmaxf(vprev[j], vcur[j]);
        #pragma unroll
        for (int j = 0; j < 9; ++j)
            lds[tid * 81 + (i - 1) * 9 + j] = fmaxf(rm[j], rm[j + 1]);
        #pragma unroll
        for (int j = 0; j < 10; ++j) vprev[j] = vcur[j];
        if (i < 9) {
            #pragma unroll
            for (int j = 0; j < 10; ++j) raw1[j] = rawn[j];
        }
    }
    __syncthreads();                               // single wave: just an lgkmcnt drain

    // LDS mirrors out[r][q*64.. ][81] exactly: pure vector copy, no index math.
    const float4* lds4 = reinterpret_cast<const float4*>(lds);
    float4* dst4 = reinterpret_cast<float4*>(out + (size_t)r * 20736 + q * 5184);
    #pragma unroll
    for (int k = 0; k < 20; ++k)
        dst4[tid + (k << 6)] = lds4[tid + (k << 6)];
    if (tid < 16)                                  // 64*81/4 = 1296 = 20*64 + 16
        dst4[tid + 1280] = lds4[tid + 1280];
}

extern "C" void kernel_launch(void* const* d_in, const int* in_sizes, int n_in,
                              void* d_out, int out_size, void* d_ws, size_t ws_size,
                              hipStream_t stream) {
    const float* F    = (const float*)d_in[0];   // 4*256*64*64
    const float* rois = (const float*)d_in[1];   // 2048*5
    float*       out  = (float*)d_out;           // 2048*256*9*9
    float*       G    = (float*)d_ws;            // 4*100*256 floats = 409600 B

    rod_gather<<<dim3(400), dim3(256), 0, stream>>>(F, G);
    rod_main<<<dim3(NR * 4), dim3(64), 0, stream>>>(G, rois, out);
}